// Round 1
// 159.308 us; speedup vs baseline: 1.0767x; 1.0767x over previous
//
#include <hip/hip_runtime.h>

#define N_USER 100000
#define N_ITEM 50000
#define N_NODES 150000
#define EMB 64
#define NNZ 4000000
#define BATCH 4096
#define NSLOTS (3 * BATCH)          // 12288 output slots / compact ids
#define CAP 128                     // bucket capacity per compact row (λ≈26.7)

// ws layout (bytes). Everything below ZERO_BYTES is zero-initialized by ONE
// memset (ctab uses cid+1 encoding so 0 == unclaimed; lists use slot+1, 0 == end).
//   BM_OFF  : bitmask, 150000 bits -> 18752 B (L1-resident during scatter)
//   CUR_OFF : per-compact-row cursors, 12288 u32
//   HEAD_OFF: cid -> first slot+1 (linked list head), 12288 u32
//   NEXT_OFF: slot -> next slot+1, 12288 u32
//   CT_OFF  : node -> cid+1, 150000 i32 (0 = unclaimed)
//   BKT_OFF : buckets, 12288 x CAP x 8 B = 12.6 MB (not cleared; cursor-guarded)
#define BM_OFF    0
#define CUR_OFF   19200
#define HEAD_OFF  68352
#define NEXT_OFF  117504
#define CT_OFF    166656
#define ZERO_BYTES 766656
#define BKT_OFF   768000

typedef int   i32x4 __attribute__((ext_vector_type(4)));
typedef float f32x4 __attribute__((ext_vector_type(4)));

// K1: one thread per output slot: set node bit, claim compact id (CAS winner),
// and push this slot onto the winner-cid's linked list (atomicExch).
__global__ void mark_kernel(const int* __restrict__ users,
                            const int* __restrict__ pos_items,
                            const int* __restrict__ neg_items,
                            unsigned int* __restrict__ bitmask,
                            int* __restrict__ ctab,
                            int* __restrict__ head,
                            int* __restrict__ next) {
    int t = blockIdx.x * blockDim.x + threadIdx.x;   // NSLOTS threads
    int k = t >> 12;
    int i = t & 4095;
    int node;
    if (k == 0)      node = users[i];
    else if (k == 1) node = N_USER + pos_items[i];
    else             node = N_USER + neg_items[i];
    atomicOr(bitmask + (node >> 5), 1u << (node & 31));
    int w = atomicCAS(ctab + node, 0, t + 1);        // 0 = unclaimed
    int cid = (w == 0) ? t : (w - 1);                // exactly one winner per node
    next[t] = atomicExch(head + cid, t + 1);         // push slot onto cid's list
}

// K2: stream 4M edges, 4 per thread (16 B/lane NT loads); ~8% needed edges
// drop an 8 B (col,val) record into their row's bucket.
__device__ __forceinline__ void scatter_edge(int row, int col, float val,
                                             const unsigned int* __restrict__ bitmask,
                                             const int* __restrict__ ctab,
                                             unsigned int* __restrict__ cursor,
                                             uint2* __restrict__ bucket) {
    unsigned int w = bitmask[row >> 5];
    if ((w >> (row & 31)) & 1) {
        int cid = ctab[row] - 1;                     // claimed: >0 guaranteed
        unsigned int pos = atomicAdd(cursor + cid, 1u);
        if (pos < CAP)                               // overflow guard (P~1e-40)
            bucket[(size_t)cid * CAP + pos] =
                make_uint2((unsigned int)col, __float_as_uint(val));
    }
}

__global__ void scatter_kernel(const i32x4* __restrict__ rows4,
                               const i32x4* __restrict__ cols4,
                               const f32x4* __restrict__ vals4,
                               const unsigned int* __restrict__ bitmask,
                               const int* __restrict__ ctab,
                               unsigned int* __restrict__ cursor,
                               uint2* __restrict__ bucket) {
    int t = blockIdx.x * blockDim.x + threadIdx.x;   // 1,000,000 threads (guarded)
    if (t >= NNZ / 4) return;
    i32x4 r = __builtin_nontemporal_load(rows4 + t);
    i32x4 c = __builtin_nontemporal_load(cols4 + t);
    f32x4 v = __builtin_nontemporal_load(vals4 + t);
    #pragma unroll
    for (int j = 0; j < 4; j++)
        scatter_edge(r[j], c[j], v[j], bitmask, ctab, cursor, bucket);
}

// K3 (fused accum+gather): one wave per compact id. Accumulate bucket entries
// in registers (8 independent 256 B gathers in flight), then walk the cid's
// slot list writing out[slot] = (ego + 3*acc)/4 directly. No prop buffer.
__global__ void accum_kernel(const unsigned int* __restrict__ cursor,
                             const uint2* __restrict__ bucket,
                             const float* __restrict__ user_emb,
                             const float* __restrict__ item_emb,
                             const int* __restrict__ head,
                             const int* __restrict__ next,
                             const int* __restrict__ users,
                             const int* __restrict__ pos_items,
                             const int* __restrict__ neg_items,
                             float* __restrict__ out) {
    int t = blockIdx.x * blockDim.x + threadIdx.x;   // NSLOTS waves
    int wv = t >> 6;
    int lane = t & 63;
    int h = head[wv];
    if (h == 0) return;                              // cid unclaimed: no output
    unsigned int n = cursor[wv];
    if (n > CAP) n = CAP;
    const uint2* bkt = bucket + (size_t)wv * CAP;
    float acc = 0.0f;
    for (unsigned int base = 0; base < n; base += 8) {
        #pragma unroll
        for (int u = 0; u < 8; u++) {
            unsigned int e = base + (unsigned int)u;
            uint2 ev = bkt[e < n ? e : n - 1];       // wave-uniform address
            int c = (int)ev.x;
            float v = __uint_as_float(ev.y);
            const float* x = (c < N_USER) ? user_emb + (size_t)c * EMB
                                          : item_emb + (size_t)(c - N_USER) * EMB;
            float xv = x[lane];                      // 64-lane 256 B gather
            acc += (e < n) ? v * xv : 0.0f;
        }
    }
    float p3 = 3.0f * acc;
    int s = h - 1;                                   // walk slot list (avg len 1.06)
    while (true) {
        int k = s >> 12;
        int i = s & 4095;
        int node;
        if (k == 0)      node = users[i];
        else if (k == 1) node = N_USER + pos_items[i];
        else             node = N_USER + neg_items[i];
        const float* ego = (node < N_USER) ? user_emb + (size_t)node * EMB
                                           : item_emb + (size_t)(node - N_USER) * EMB;
        out[(size_t)s * EMB + lane] = (ego[lane] + p3) * 0.25f;
        int nx = next[s];
        if (nx == 0) break;
        s = nx - 1;
    }
}

extern "C" void kernel_launch(void* const* d_in, const int* in_sizes, int n_in,
                              void* d_out, int out_size, void* d_ws, size_t ws_size,
                              hipStream_t stream) {
    const int*   adj_rows = (const int*)  d_in[0];
    const int*   adj_cols = (const int*)  d_in[1];
    const float* adj_vals = (const float*)d_in[2];
    const float* user_emb = (const float*)d_in[3];
    const float* item_emb = (const float*)d_in[4];
    const int*   users    = (const int*)  d_in[5];
    const int*   pos      = (const int*)  d_in[6];
    const int*   neg      = (const int*)  d_in[7];
    float* out = (float*)d_out;

    unsigned int* bitmask = (unsigned int*)((char*)d_ws + BM_OFF);
    unsigned int* cursor  = (unsigned int*)((char*)d_ws + CUR_OFF);
    int*          head    = (int*)         ((char*)d_ws + HEAD_OFF);
    int*          next    = (int*)         ((char*)d_ws + NEXT_OFF);
    int*          ctab    = (int*)         ((char*)d_ws + CT_OFF);
    uint2*        bucket  = (uint2*)       ((char*)d_ws + BKT_OFF);

    // Single zero-fill covers bitmask + cursors + heads + nexts + ctab.
    hipMemsetAsync(d_ws, 0, ZERO_BYTES, stream);

    // NSLOTS = 12288 threads -> 48 blocks of 256
    mark_kernel<<<48, 256, 0, stream>>>(users, pos, neg, bitmask, ctab, head, next);

    // 1,000,000 threads (4 edges each) -> 3907 blocks of 256
    scatter_kernel<<<3907, 256, 0, stream>>>((const i32x4*)adj_rows,
                                             (const i32x4*)adj_cols,
                                             (const f32x4*)adj_vals,
                                             bitmask, ctab, cursor, bucket);

    // NSLOTS waves = 786432 threads -> 3072 blocks of 256
    accum_kernel<<<3072, 256, 0, stream>>>(cursor, bucket, user_emb, item_emb,
                                           head, next, users, pos, neg, out);
}